// Round 10
// baseline (1545.898 us; speedup 1.0000x reference)
//
#include <hip/hip_runtime.h>
#include <hip/hip_bf16.h>

#define NN 100000
#define NE 100000
#define NCNT (14 * NN)
#define LP 136    // padded LDS pitch (bf16) for encoder kernels
#define LP2 168   // pitch for K=160 (meta)
#define SCAN_CHUNK 4096
#define NSCB ((NCNT + SCAN_CHUNK - 1) / SCAN_CHUNK)

typedef __bf16 bf16;
typedef __bf16 bf16x8 __attribute__((ext_vector_type(8)));
typedef float  f32x4  __attribute__((ext_vector_type(4)));
typedef unsigned long long u64;

// ---------- generic helpers ----------

__device__ __forceinline__ void zacc8(f32x4 acc[8]) {
    f32x4 z = {0.f, 0.f, 0.f, 0.f};
#pragma unroll
    for (int n = 0; n < 8; ++n) acc[n] = z;
}

// per-wave GroupNorm(1) stats (encoder kernels): wave holds 16 full rows
__device__ __forceinline__ void gnstats(const f32x4 acc[8], float mean[4], float rs[4]) {
    float s1[4], s2[4];
#pragma unroll
    for (int r = 0; r < 4; ++r) { s1[r] = 0.f; s2[r] = 0.f; }
#pragma unroll
    for (int n = 0; n < 8; ++n)
#pragma unroll
        for (int r = 0; r < 4; ++r) { float v = acc[n][r]; s1[r] += v; s2[r] += v * v; }
#pragma unroll
    for (int off = 1; off < 16; off <<= 1) {
#pragma unroll
        for (int r = 0; r < 4; ++r) {
            s1[r] += __shfl_xor(s1[r], off, 64);
            s2[r] += __shfl_xor(s2[r], off, 64);
        }
    }
#pragma unroll
    for (int r = 0; r < 4; ++r) {
        const float m = s1[r] * 0.0078125f;
        const float v = fmaxf(s2[r] * 0.0078125f - m * m, 0.f);
        mean[r] = m;
        rs[r] = rsqrtf(v + 1e-5f);
    }
}

// ---------- encoder-path helpers ----------

template<int PITCH, int COLS>
__device__ inline void stageWB(const bf16* __restrict__ Wg, bf16* Wl) {
    constexpr int NV = 128 * COLS / 8;
    for (int i = threadIdx.x; i < NV; i += 256) {
        const int e = i * 8;
        const int r = e / COLS, c = e % COLS;
        *(float4*)(&Wl[r * PITCH + c]) = ((const float4*)Wg)[i];
    }
}

template<int PITCH, int KSTEPS>
__device__ inline void mmaT(const bf16* Al, const bf16* Wl, int m0, int lane, f32x4 acc[8]) {
#pragma unroll
    for (int kk = 0; kk < KSTEPS; ++kk) {
        bf16x8 a = *(const bf16x8*)(&Al[(m0 + (lane & 15)) * PITCH + kk * 32 + (lane >> 4) * 8]);
#pragma unroll
        for (int n = 0; n < 8; ++n) {
            bf16x8 b = *(const bf16x8*)(&Wl[(n * 16 + (lane & 15)) * PITCH + kk * 32 + (lane >> 4) * 8]);
            acc[n] = __builtin_amdgcn_mfma_f32_16x16x32_bf16(a, b, acc[n], 0, 0, 0);
        }
    }
}

// ---------- weight conversion + nodes output slice (one kernel) ----------

__global__ __launch_bounds__(256) void k_cvt_all(
    const float* __restrict__ in2W, const float* __restrict__ seg2W,
    const float* __restrict__ metaW, const float* __restrict__ ctrW,
    const float* __restrict__ ctr2W, const float* __restrict__ edgeW,
    bf16* __restrict__ wIn2, bf16* __restrict__ wSeg2, bf16* __restrict__ wMeta,
    bf16* __restrict__ wCtr, bf16* __restrict__ wCtr2, bf16* __restrict__ wEdge,
    const float* __restrict__ nodes, float* __restrict__ outp)
{
    for (int j = blockIdx.x * 256 + threadIdx.x; j < 2 * NN; j += gridDim.x * 256)
        outp[(size_t)NN * 128 + j] = nodes[(size_t)(j >> 1) * 8 + (j & 1)];
    const int total = 16384 + 16384 + 20480 + 65536 + 65536 + 917504;
    for (int i = blockIdx.x * 256 + threadIdx.x; i < total; i += gridDim.x * 256) {
        int j = i;
        if (j < 16384) { wIn2[j] = (bf16)in2W[j]; continue; }
        j -= 16384;
        if (j < 16384) { wSeg2[j] = (bf16)seg2W[j]; continue; }
        j -= 16384;
        if (j < 20480) {
            const int r = j / 160, c = j % 160;
            wMeta[j] = (bf16)(c < 132 ? metaW[r * 132 + c] : 0.f);
            continue;
        }
        j -= 20480;
        if (j < 65536) { wCtr[j] = (bf16)ctrW[j]; continue; }
        j -= 65536;
        if (j < 65536) { wCtr2[j] = (bf16)ctr2W[j]; continue; }
        j -= 65536;
        wEdge[j] = (bf16)edgeW[j];
    }
}

// ---------- CSR build ----------

__global__ __launch_bounds__(256) void k_count(const int* __restrict__ idx,
                                               const int* __restrict__ mask,
                                               int* __restrict__ cnt) {
    __shared__ int lim[14];
    if (threadIdx.x < 14) lim[threadIdx.x] = min(mask[threadIdx.x], NE);
    __syncthreads();
    for (int i = blockIdx.x * 256 + threadIdx.x; i < 14 * NE; i += gridDim.x * 256) {
        const int e = i / 14, t = i - e * 14;
        if (e < lim[t]) atomicAdd(&cnt[t * NN + idx[(size_t)e * 28 + 2 * t]], 1);
    }
}

__global__ __launch_bounds__(256) void k_scanA(const int* __restrict__ cnt,
                                               int* __restrict__ ptr,
                                               int* __restrict__ tot) {
    __shared__ int sm[256];
    const int tid = threadIdx.x;
    const int base = blockIdx.x * SCAN_CHUNK + tid * 16;
    int v[16]; int run = 0;
#pragma unroll
    for (int j = 0; j < 16; ++j) {
        const int x = (base + j < NCNT) ? cnt[base + j] : 0;
        v[j] = run; run += x;
    }
    sm[tid] = run; __syncthreads();
    for (int d = 1; d < 256; d <<= 1) {
        int t = 0;
        if (tid >= d) t = sm[tid - d];
        __syncthreads();
        sm[tid] += t;
        __syncthreads();
    }
    const int off = sm[tid] - run;
#pragma unroll
    for (int j = 0; j < 16; ++j)
        if (base + j < NCNT) ptr[base + j] = v[j] + off;
    if (tid == 255) tot[blockIdx.x] = sm[255];
}

__global__ void k_scanB(int* __restrict__ tot) {
    if (threadIdx.x == 0 && blockIdx.x == 0) {
        int acc = 0;
        for (int b = 0; b < NSCB; ++b) { const int t = tot[b]; tot[b] = acc; acc += t; }
        tot[NSCB] = acc;
    }
}

__global__ __launch_bounds__(256) void k_scanC(int* __restrict__ ptr,
                                               int* __restrict__ cursor,
                                               const int* __restrict__ tot) {
    const int base = blockIdx.x * SCAN_CHUNK;
    const int o = tot[blockIdx.x];
    for (int j = threadIdx.x; j < SCAN_CHUNK; j += 256) {
        const int i = base + j;
        if (i < NCNT) { const int p = ptr[i] + o; ptr[i] = p; cursor[i] = p; }
    }
    if (blockIdx.x == 0 && threadIdx.x == 0) ptr[NCNT] = tot[NSCB];
}

// elist entry: (edge_id << 32) | src
__global__ __launch_bounds__(256) void k_fill(const int* __restrict__ idx,
                                              const int* __restrict__ mask,
                                              int* __restrict__ cursor,
                                              u64* __restrict__ el) {
    __shared__ int lim[14];
    if (threadIdx.x < 14) lim[threadIdx.x] = min(mask[threadIdx.x], NE);
    __syncthreads();
    for (int i = blockIdx.x * 256 + threadIdx.x; i < 14 * NE; i += gridDim.x * 256) {
        const int e = i / 14, t = i - e * 14;
        if (e < lim[t]) {
            const int dst = idx[(size_t)e * 28 + 2 * t];
            const int src = idx[(size_t)e * 28 + 2 * t + 1];
            const int pos = atomicAdd(&cursor[t * NN + dst], 1);
            el[pos] = ((u64)(unsigned)e << 32) | (unsigned)src;
        }
    }
}

__global__ __launch_bounds__(256) void k_sortseg(const int* __restrict__ ptr,
                                                 u64* __restrict__ el) {
    for (int i = blockIdx.x * 256 + threadIdx.x; i < NCNT; i += gridDim.x * 256) {
        const int s = ptr[i], e2 = ptr[i + 1];
        for (int a = s + 1; a < e2; ++a) {
            const u64 key = el[a];
            int b = a - 1;
            while (b >= s && el[b] > key) { el[b + 1] = el[b]; --b; }
            el[b + 1] = key;
        }
    }
}

// ---------- input encoder ----------

__global__ __launch_bounds__(256) void k_in(
    const float* __restrict__ nodes,
    const float* __restrict__ in1W, const float* __restrict__ in1b,
    const bf16* __restrict__ wIn2,
    const float* __restrict__ ing, const float* __restrict__ inbg,
    const float* __restrict__ seg1W, const float* __restrict__ seg1b,
    const bf16* __restrict__ wSeg2,
    const float* __restrict__ segg, const float* __restrict__ segbg,
    bf16* __restrict__ outPre)
{
    __shared__ __align__(16) bf16 Wl[128 * LP];
    __shared__ __align__(16) bf16 Al[64 * LP];
    __shared__ float w0[128], w1[128], bb[128];
    __shared__ float xs[64][4];
    const int tid = threadIdx.x;
    const int row0 = blockIdx.x * 64;
    if (tid < 64) {
        const int row = row0 + tid;
        float4 x = {0.f, 0.f, 0.f, 0.f};
        if (row < NN) x = *(const float4*)(nodes + (size_t)row * 8);
        xs[tid][0] = x.x; xs[tid][1] = x.y; xs[tid][2] = x.z; xs[tid][3] = x.w;
    }
    if (tid < 128) { w0[tid] = in1W[tid * 2]; w1[tid] = in1W[tid * 2 + 1]; bb[tid] = in1b[tid]; }
    stageWB<LP, 128>(wIn2, Wl);
    __syncthreads();
    for (int i = tid; i < 64 * 128; i += 256) {
        const int r = i >> 7, j = i & 127;
        Al[r * LP + j] = (bf16)fmaxf(xs[r][0] * w0[j] + xs[r][1] * w1[j] + bb[j], 0.f);
    }
    __syncthreads();
    const int lane = tid & 63, m0 = (tid >> 6) * 16;
    f32x4 accP[8]; zacc8(accP);
    mmaT<LP, 4>(Al, Wl, m0, lane, accP);
    __syncthreads();
    if (tid < 128) { w0[tid] = seg1W[tid * 2]; w1[tid] = seg1W[tid * 2 + 1]; bb[tid] = seg1b[tid]; }
    stageWB<LP, 128>(wSeg2, Wl);
    __syncthreads();
    for (int i = tid; i < 64 * 128; i += 256) {
        const int r = i >> 7, j = i & 127;
        Al[r * LP + j] = (bf16)fmaxf(xs[r][2] * w0[j] + xs[r][3] * w1[j] + bb[j], 0.f);
    }
    __syncthreads();
    f32x4 accQ[8]; zacc8(accQ);
    mmaT<LP, 4>(Al, Wl, m0, lane, accQ);

    float mP[4], rP[4], mQ[4], rQ[4];
    gnstats(accP, mP, rP);
    gnstats(accQ, mQ, rQ);
    float gP[8], bP[8], gQ[8], bQ[8];
#pragma unroll
    for (int n = 0; n < 8; ++n) {
        const int c = n * 16 + (lane & 15);
        gP[n] = ing[c]; bP[n] = inbg[c]; gQ[n] = segg[c]; bQ[n] = segbg[c];
    }
#pragma unroll
    for (int r = 0; r < 4; ++r) {
        const int row = row0 + m0 + (lane >> 4) * 4 + r;
        if (row < NN) {
#pragma unroll
            for (int n = 0; n < 8; ++n) {
                const float yp = (accP[n][r] - mP[r]) * rP[r] * gP[n] + bP[n];
                const float yq = (accQ[n][r] - mQ[r]) * rQ[r] * gQ[n] + bQ[n];
                outPre[(size_t)row * 128 + n * 16 + (lane & 15)] = (bf16)fmaxf(yp + yq, 0.f);
            }
        }
    }
}

// ---------- meta ----------

__global__ __launch_bounds__(256) void k_meta(
    const bf16* __restrict__ Apre, const float* __restrict__ nodes,
    const bf16* __restrict__ Wg,
    const float* __restrict__ g, const float* __restrict__ bg,
    bf16* __restrict__ featB)
{
    __shared__ __align__(16) bf16 Wl[128 * LP2];
    __shared__ __align__(16) bf16 Al[64 * LP2];
    const int row0 = blockIdx.x * 64;
    stageWB<LP2, 160>(Wg, Wl);
    {
        const int r = threadIdx.x >> 2, q = threadIdx.x & 3;
        float4* d = (float4*)(&Al[r * LP2 + q * 32]);
        const int row = row0 + r;
        if (row < NN) {
            const float4* s = (const float4*)(Apre + (size_t)row * 128 + q * 32);
            float4 a0 = s[0], a1 = s[1], a2 = s[2], a3 = s[3];
            d[0] = a0; d[1] = a1; d[2] = a2; d[3] = a3;
        } else {
            float4 z = {0.f, 0.f, 0.f, 0.f};
            d[0] = z; d[1] = z; d[2] = z; d[3] = z;
        }
    }
    if (threadIdx.x < 64) {
        const int rr = threadIdx.x, row = row0 + rr;
        bf16* d = &Al[rr * LP2 + 128];
        if (row < NN) {
            const float4 x = *(const float4*)(nodes + (size_t)row * 8 + 4);
            d[0] = (bf16)x.x; d[1] = (bf16)x.y; d[2] = (bf16)x.z; d[3] = (bf16)x.w;
        } else {
            d[0] = (bf16)0.f; d[1] = (bf16)0.f; d[2] = (bf16)0.f; d[3] = (bf16)0.f;
        }
#pragma unroll
        for (int c = 4; c < 32; ++c) d[c] = (bf16)0.f;
    }
    __syncthreads();
    const int lane = threadIdx.x & 63, m0 = (threadIdx.x >> 6) * 16;
    f32x4 acc[8]; zacc8(acc);
    mmaT<LP2, 5>(Al, Wl, m0, lane, acc);

    float mean[4], rs[4];
    gnstats(acc, mean, rs);
    float gv[8], bv[8];
#pragma unroll
    for (int n = 0; n < 8; ++n) { const int c = n * 16 + (lane & 15); gv[n] = g[c]; bv[n] = bg[c]; }
#pragma unroll
    for (int r = 0; r < 4; ++r) {
        const int row = row0 + m0 + (lane >> 4) * 4 + r;
        if (row < NN) {
            const size_t off = (size_t)row * 128 + (lane & 15);
#pragma unroll
            for (int n = 0; n < 8; ++n) {
                const float y = (acc[n][r] - mean[r]) * rs[r] * gv[n] + bv[n];
                featB[off + n * 16] = (bf16)fmaxf(y, 0.f);
            }
        }
    }
}

// ---------- fused round: gather pipelined, 4-src prefetched heads issued pre-barrier ----------
// M=64/block, 512 threads = 8 waves; wave w owns output cols w*16..w*16+15.
// deg<=4 (98.5% of rows) fully covered by prefetched independent loads;
// serial tail only for deg>4 (~21% of block-phases see any).

__global__ __launch_bounds__(512, 2) void k_round(
    const bf16* __restrict__ feat,
    const int* __restrict__ ptr,
    const int* __restrict__ sl32,      // u64 elist as int pairs; src = sl32[2*j]
    const bf16* __restrict__ wEdgeR,   // 14 * 16384
    const bf16* __restrict__ wCtrR,
    const bf16* __restrict__ wCtr2R,
    const float* __restrict__ ng, const float* __restrict__ nbg,
    const float* __restrict__ c2g, const float* __restrict__ c2bg,
    bf16* __restrict__ featOut,
    float* __restrict__ outF,
    int last)
{
    __shared__ __align__(16) bf16 AT[2][64 * 128];   // 2 x 16KB A tiles
    __shared__ float red[8 * 64 * 2];                // per-wave GN partials
    __shared__ float stats[64 * 2];                  // mean, rsqrt per row

    const int tid = threadIdx.x;
    const int w = tid >> 6, lane = tid & 63;
    const int r = lane & 15, h = lane >> 4, r7 = r & 7;
    const int n0 = w * 16;                 // wave's output column base
    const int row0 = blockIdx.x * 64;

    // gather role: 8 threads per row, 32B (16 bf16) slice each
    const int rr = tid >> 3, sl = tid & 7;
    const int grow = row0 + rr;
    const bool rowok = grow < NN;
    const int wb0 = rr * 256 + (((2 * sl)     ^ (rr & 7)) * 16);
    const int wb1 = rr * 256 + (((2 * sl + 1) ^ (rr & 7)) * 16);

    // CSR state: (p0,p1,s0..s3) = segment to gather next; (np0,np1) = one after
    int p0 = 0, p1 = 0;
    if (rowok) { p0 = ptr[grow]; p1 = ptr[grow + 1]; }
    int s0 = 0, s1 = 0, s2 = 0, s3 = 0;
    {
        const int d = p1 - p0;
        if (d > 0) s0 = sl32[2 * p0];
        if (d > 1) s1 = sl32[2 * (p0 + 1)];
        if (d > 2) s2 = sl32[2 * (p0 + 2)];
        if (d > 3) s3 = sl32[2 * (p0 + 3)];
    }
    int np0 = 0, np1 = 0;
    if (rowok) { np0 = ptr[NN + grow]; np1 = ptr[NN + grow + 1]; }

    const char* fb = (const char*)feat;
    float ag[16];

    // ---- preloop: gather type 0 into ag (latency exposed once) ----
    {
        const int d = p1 - p0;
        bf16x8 ea0, ea1, eb0, eb1, ec0, ec1, ed0, ed1;
        if (d > 0) { const bf16x8* q = (const bf16x8*)(fb + (size_t)s0 * 256 + sl * 32); ea0 = q[0]; ea1 = q[1]; }
        if (d > 1) { const bf16x8* q = (const bf16x8*)(fb + (size_t)s1 * 256 + sl * 32); eb0 = q[0]; eb1 = q[1]; }
        if (d > 2) { const bf16x8* q = (const bf16x8*)(fb + (size_t)s2 * 256 + sl * 32); ec0 = q[0]; ec1 = q[1]; }
        if (d > 3) { const bf16x8* q = (const bf16x8*)(fb + (size_t)s3 * 256 + sl * 32); ed0 = q[0]; ed1 = q[1]; }
        int u0 = 0, u1 = 0, u2 = 0, u3 = 0;
        {
            const int dn = np1 - np0;
            if (dn > 0) u0 = sl32[2 * np0];
            if (dn > 1) u1 = sl32[2 * (np0 + 1)];
            if (dn > 2) u2 = sl32[2 * (np0 + 2)];
            if (dn > 3) u3 = sl32[2 * (np0 + 3)];
        }
        int q0 = 0, q1 = 0;
        if (rowok) { const size_t b2 = (size_t)2 * NN + grow; q0 = ptr[b2]; q1 = ptr[b2 + 1]; }
#pragma unroll
        for (int j = 0; j < 16; ++j) ag[j] = 0.f;
        if (d > 0) {
#pragma unroll
            for (int j = 0; j < 8; ++j) { ag[j] += (float)ea0[j]; ag[8 + j] += (float)ea1[j]; }
        }
        if (d > 1) {
#pragma unroll
            for (int j = 0; j < 8; ++j) { ag[j] += (float)eb0[j]; ag[8 + j] += (float)eb1[j]; }
        }
        if (d > 2) {
#pragma unroll
            for (int j = 0; j < 8; ++j) { ag[j] += (float)ec0[j]; ag[8 + j] += (float)ec1[j]; }
        }
        if (d > 3) {
#pragma unroll
            for (int j = 0; j < 8; ++j) { ag[j] += (float)ed0[j]; ag[8 + j] += (float)ed1[j]; }
        }
        for (int j2 = p0 + 4; j2 < p1; j2 += 2) {
            { const bf16x8* q = (const bf16x8*)(fb + (size_t)sl32[2 * j2] * 256 + sl * 32); ea0 = q[0]; ea1 = q[1]; }
            const bool two = (j2 + 1 < p1);
            if (two) { const bf16x8* q = (const bf16x8*)(fb + (size_t)sl32[2 * (j2 + 1)] * 256 + sl * 32); eb0 = q[0]; eb1 = q[1]; }
#pragma unroll
            for (int j = 0; j < 8; ++j) { ag[j] += (float)ea0[j]; ag[8 + j] += (float)ea1[j]; }
            if (two) {
#pragma unroll
                for (int j = 0; j < 8; ++j) { ag[j] += (float)eb0[j]; ag[8 + j] += (float)eb1[j]; }
            }
        }
        p0 = np0; p1 = np1; s0 = u0; s1 = u1; s2 = u2; s3 = u3; np0 = q0; np1 = q1;
    }

    f32x4 acc[4];
    { f32x4 z = {0.f, 0.f, 0.f, 0.f}; acc[0] = z; acc[1] = z; acc[2] = z; acc[3] = z; }

    for (int t = 0; t < 15; ++t) {
        // write ag (aggregate for type t) into AT[t&1]
        {
            bf16x8 av0, av1;
#pragma unroll
            for (int j = 0; j < 8; ++j) { av0[j] = (bf16)ag[j]; av1[j] = (bf16)ag[8 + j]; }
            char* atb = (char*)AT[t & 1];
            *(bf16x8*)(atb + wb0) = av0;
            *(bf16x8*)(atb + wb1) = av1;
        }
        // B fragments for this phase (global; latency hidden by barrier wait)
        const bf16* Wt = (t < 14) ? (wEdgeR + (size_t)t * 16384) : wCtrR;
        bf16x8 bfr[4];
#pragma unroll
        for (int kk = 0; kk < 4; ++kk)
            bfr[kk] = *(const bf16x8*)(Wt + (n0 + r) * 128 + kk * 32 + h * 8);

        // issue next-phase gather head loads + index prefetch BEFORE the barrier:
        // they are vmem-only, unaffected by the lgkmcnt drain, and their latency
        // hides under barrier-wait + MFMA.
        const int tt = t + 1;
        bf16x8 ea0, ea1, eb0, eb1, ec0, ec1, ed0, ed1;
        int d = 0, u0 = 0, u1 = 0, u2 = 0, u3 = 0, q0 = 0, q1 = 0;
        if (tt < 14) {
            d = p1 - p0;
            if (d > 0) { const bf16x8* q = (const bf16x8*)(fb + (size_t)s0 * 256 + sl * 32); ea0 = q[0]; ea1 = q[1]; }
            if (d > 1) { const bf16x8* q = (const bf16x8*)(fb + (size_t)s1 * 256 + sl * 32); eb0 = q[0]; eb1 = q[1]; }
            if (d > 2) { const bf16x8* q = (const bf16x8*)(fb + (size_t)s2 * 256 + sl * 32); ec0 = q[0]; ec1 = q[1]; }
            if (d > 3) { const bf16x8* q = (const bf16x8*)(fb + (size_t)s3 * 256 + sl * 32); ed0 = q[0]; ed1 = q[1]; }
            if (tt <= 12) {
                const int dn = np1 - np0;
                if (dn > 0) u0 = sl32[2 * np0];
                if (dn > 1) u1 = sl32[2 * (np0 + 1)];
                if (dn > 2) u2 = sl32[2 * (np0 + 2)];
                if (dn > 3) u3 = sl32[2 * (np0 + 3)];
            }
            if (tt <= 11 && rowok) {
                const size_t b2 = (size_t)(tt + 2) * NN + grow;
                q0 = ptr[b2]; q1 = ptr[b2 + 1];
            }
        } else if (tt == 14) {
            // ctr self-term: own feat row
            if (rowok) { const bf16x8* q = (const bf16x8*)(fb + (size_t)grow * 256 + sl * 32); ea0 = q[0]; ea1 = q[1]; d = 1; }
        }

        asm volatile("s_waitcnt lgkmcnt(0)" ::: "memory");  // LDS writes visible
        __builtin_amdgcn_s_barrier();                       // (global loads stay in flight)
        __builtin_amdgcn_sched_barrier(0);

        // MFMA[t] from AT[t&1]
        {
            const char* atr = (const char*)AT[t & 1];
#pragma unroll
            for (int m = 0; m < 4; ++m) {
                const int arow = m * 16 + r;
#pragma unroll
                for (int kk = 0; kk < 4; ++kk) {
                    const bf16x8 a = *(const bf16x8*)(atr + arow * 256 + (((kk * 4 + h) ^ r7) * 16));
                    acc[m] = __builtin_amdgcn_mfma_f32_16x16x32_bf16(a, bfr[kk], acc[m], 0, 0, 0);
                }
            }
        }

        // finish gather for tt (accumulate heads + rare serial tail for deg>4)
        if (tt <= 14) {
#pragma unroll
            for (int j = 0; j < 16; ++j) ag[j] = 0.f;
            if (d > 0) {
#pragma unroll
                for (int j = 0; j < 8; ++j) { ag[j] += (float)ea0[j]; ag[8 + j] += (float)ea1[j]; }
            }
            if (tt < 14) {
                if (d > 1) {
#pragma unroll
                    for (int j = 0; j < 8; ++j) { ag[j] += (float)eb0[j]; ag[8 + j] += (float)eb1[j]; }
                }
                if (d > 2) {
#pragma unroll
                    for (int j = 0; j < 8; ++j) { ag[j] += (float)ec0[j]; ag[8 + j] += (float)ec1[j]; }
                }
                if (d > 3) {
#pragma unroll
                    for (int j = 0; j < 8; ++j) { ag[j] += (float)ed0[j]; ag[8 + j] += (float)ed1[j]; }
                }
                for (int j2 = p0 + 4; j2 < p1; j2 += 2) {
                    { const bf16x8* q = (const bf16x8*)(fb + (size_t)sl32[2 * j2] * 256 + sl * 32); ea0 = q[0]; ea1 = q[1]; }
                    const bool two = (j2 + 1 < p1);
                    if (two) { const bf16x8* q = (const bf16x8*)(fb + (size_t)sl32[2 * (j2 + 1)] * 256 + sl * 32); eb0 = q[0]; eb1 = q[1]; }
#pragma unroll
                    for (int j = 0; j < 8; ++j) { ag[j] += (float)ea0[j]; ag[8 + j] += (float)ea1[j]; }
                    if (two) {
#pragma unroll
                        for (int j = 0; j < 8; ++j) { ag[j] += (float)eb0[j]; ag[8 + j] += (float)eb1[j]; }
                    }
                }
                p0 = np0; p1 = np1; s0 = u0; s1 = u1; s2 = u2; s3 = u3; np0 = q0; np1 = q1;
            }
        }
    }

    // ---- GN 1: cross-wave reduction (rows split across waves) ----
#pragma unroll
    for (int m = 0; m < 4; ++m) {
        float a1[4], a2[4];
#pragma unroll
        for (int g2 = 0; g2 < 4; ++g2) { const float v = acc[m][g2]; a1[g2] = v; a2[g2] = v * v; }
#pragma unroll
        for (int off = 1; off < 16; off <<= 1)
#pragma unroll
            for (int g2 = 0; g2 < 4; ++g2) {
                a1[g2] += __shfl_xor(a1[g2], off, 64);
                a2[g2] += __shfl_xor(a2[g2], off, 64);
            }
        if (r == 0) {
#pragma unroll
            for (int g2 = 0; g2 < 4; ++g2) {
                const int row = m * 16 + h * 4 + g2;
                red[(w * 64 + row) * 2]     = a1[g2];
                red[(w * 64 + row) * 2 + 1] = a2[g2];
            }
        }
    }
    __syncthreads();
    if (tid < 64) {
        float s1 = 0.f, s2 = 0.f;
#pragma unroll
        for (int ww = 0; ww < 8; ++ww) { s1 += red[(ww * 64 + tid) * 2]; s2 += red[(ww * 64 + tid) * 2 + 1]; }
        const float mn = s1 * 0.0078125f;
        const float vr = fmaxf(s2 * 0.0078125f - mn * mn, 0.f);
        stats[tid * 2]     = mn;
        stats[tid * 2 + 1] = rsqrtf(vr + 1e-5f);
    }
    __syncthreads();

    // epilogue 1: y = relu(gn(acc)) -> AT[0] (swizzled bf16 A-tile); load ctr2 B
    const float gv1 = ng[n0 + r], bv1 = nbg[n0 + r];
    bf16x8 bfr2[4];
#pragma unroll
    for (int kk = 0; kk < 4; ++kk)
        bfr2[kk] = *(const bf16x8*)(wCtr2R + (n0 + r) * 128 + kk * 32 + h * 8);
    {
        char* atb = (char*)AT[0];
        const int colb = (n0 + r) * 2;
#pragma unroll
        for (int m = 0; m < 4; ++m)
#pragma unroll
            for (int g2 = 0; g2 < 4; ++g2) {
                const int row = m * 16 + h * 4 + g2;
                const float y = (acc[m][g2] - stats[row * 2]) * stats[row * 2 + 1] * gv1 + bv1;
                const int slot = (colb >> 4) ^ (row & 7);
                *(bf16*)(atb + row * 256 + slot * 16 + (colb & 15)) = (bf16)fmaxf(y, 0.f);
            }
    }
    __syncthreads();

    // ctr2 GEMM
    f32x4 ac2[4];
    { f32x4 z = {0.f, 0.f, 0.f, 0.f}; ac2[0] = z; ac2[1] = z; ac2[2] = z; ac2[3] = z; }
    {
        const char* atr = (const char*)AT[0];
#pragma unroll
        for (int m = 0; m < 4; ++m) {
            const int arow = m * 16 + r;
#pragma unroll
            for (int kk = 0; kk < 4; ++kk) {
                const bf16x8 a = *(const bf16x8*)(atr + arow * 256 + (((kk * 4 + h) ^ r7) * 16));
                ac2[m] = __builtin_amdgcn_mfma_f32_16x16x32_bf16(a, bfr2[kk], ac2[m], 0, 0, 0);
            }
        }
    }

    // ---- GN 2 ----
#pragma unroll
    for (int m = 0; m < 4; ++m) {
        float a1[4], a2[4];
#pragma unroll
        for (int g2 = 0; g2 < 4; ++g2) { const float v = ac2[m][g2]; a1[g2] = v; a2[g2] = v * v; }
#pragma unroll
        for (int off = 1; off < 16; off <<= 1)
#pragma unroll
            for (int g2 = 0; g2 < 4; ++g2) {
                a1[g2] += __shfl_xor(a1[g2], off, 64);
                a2[g2] += __shfl_xor(a2[g2], off, 64);
            }
        if (r == 0) {
#pragma unroll
            for (int g2 = 0; g2 < 4; ++g2) {
                const int row = m * 16 + h * 4 + g2;
                red[(w * 64 + row) * 2]     = a1[g2];
                red[(w * 64 + row) * 2 + 1] = a2[g2];
            }
        }
    }
    __syncthreads();
    if (tid < 64) {
        float s1 = 0.f, s2 = 0.f;
#pragma unroll
        for (int ww = 0; ww < 8; ++ww) { s1 += red[(ww * 64 + tid) * 2]; s2 += red[(ww * 64 + tid) * 2 + 1]; }
        const float mn = s1 * 0.0078125f;
        const float vr = fmaxf(s2 * 0.0078125f - mn * mn, 0.f);
        stats[tid * 2]     = mn;
        stats[tid * 2 + 1] = rsqrtf(vr + 1e-5f);
    }
    __syncthreads();

    // epilogue 2: o = relu(gn(ac2) + feat)  -> featOut (bf16) or d_out (f32)
    const float gv2 = c2g[n0 + r], bv2 = c2bg[n0 + r];
#pragma unroll
    for (int m = 0; m < 4; ++m)
#pragma unroll
        for (int g2 = 0; g2 < 4; ++g2) {
            const int row = m * 16 + h * 4 + g2;
            const int orow = row0 + row;
            if (orow < NN) {
                const size_t off = (size_t)orow * 128 + n0 + r;
                const float y = (ac2[m][g2] - stats[row * 2]) * stats[row * 2 + 1] * gv2 + bv2;
                const float o = fmaxf(y + (float)feat[off], 0.f);
                if (last) outF[off] = o;
                else      featOut[off] = (bf16)o;
            }
        }
}

// ---------- launch ----------

extern "C" void kernel_launch(void* const* d_in, const int* in_sizes, int n_in,
                              void* d_out, int out_size, void* d_ws, size_t ws_size,
                              hipStream_t stream) {
    const float* nodes  = (const float*)d_in[0];
    const int*   idx    = (const int*)d_in[1];
    const int*   mask   = (const int*)d_in[2];
    const float* in1W   = (const float*)d_in[3];
    const float* in1b   = (const float*)d_in[4];
    const float* in2W   = (const float*)d_in[5];
    const float* ing    = (const float*)d_in[6];
    const float* inbg   = (const float*)d_in[7];
    const float* seg1W  = (const float*)d_in[8];
    const float* seg1b  = (const float*)d_in[9];
    const float* seg2W  = (const float*)d_in[10];
    const float* segg   = (const float*)d_in[11];
    const float* segbg  = (const float*)d_in[12];
    const float* metaW  = (const float*)d_in[13];
    const float* metag  = (const float*)d_in[14];
    const float* metabg = (const float*)d_in[15];
    const float* ctrW   = (const float*)d_in[16];
    const float* edgeW  = (const float*)d_in[17];
    const float* normg  = (const float*)d_in[18];
    const float* normbg = (const float*)d_in[19];
    const float* ctr2W  = (const float*)d_in[20];
    const float* ctr2g  = (const float*)d_in[21];
    const float* ctr2bg = (const float*)d_in[22];
    float* out = (float*)d_out;

    char* w = (char*)d_ws;
    bf16*  featB0 = (bf16*)w;  w += (size_t)NN * 128 * 2;
    bf16*  featB1 = (bf16*)w;  w += (size_t)NN * 128 * 2;
    bf16*  preB   = (bf16*)w;  w += (size_t)NN * 128 * 2;
    bf16*  wIn2   = (bf16*)w;  w += 16384 * 2;
    bf16*  wSeg2  = (bf16*)w;  w += 16384 * 2;
    bf16*  wMeta  = (bf16*)w;  w += 20480 * 2;
    bf16*  wCtr   = (bf16*)w;  w += 65536 * 2;
    bf16*  wCtr2  = (bf16*)w;  w += 65536 * 2;
    bf16*  wEdge  = (bf16*)w;  w += (size_t)917504 * 2;
    int*   cnt    = (int*)w;   w += (size_t)NCNT * 4;
    int*   ptr    = (int*)w;   w += ((size_t)NCNT + 4) * 4;
    int*   cursor = (int*)w;   w += (size_t)NCNT * 4;
    u64*   elist  = (u64*)w;   w += (size_t)14 * NE * 8 + 64;
    int*   tot    = (int*)w;   w += (NSCB + 1) * 4;

    dim3 blk(256);
    const int gRows = (NN + 63) / 64;

    // CSR build
    hipMemsetAsync(cnt, 0, (size_t)NCNT * 4, stream);
    k_count<<<2048, blk, 0, stream>>>(idx, mask, cnt);
    k_scanA<<<NSCB, blk, 0, stream>>>(cnt, ptr, tot);
    k_scanB<<<1, 64, 0, stream>>>(tot);
    k_scanC<<<NSCB, blk, 0, stream>>>(ptr, cursor, tot);
    k_fill<<<2048, blk, 0, stream>>>(idx, mask, cursor, elist);
    k_sortseg<<<2048, blk, 0, stream>>>(ptr, elist);

    // weights -> bf16 (+ nodes slice of the output)
    k_cvt_all<<<1024, blk, 0, stream>>>(in2W, seg2W, metaW, ctrW, ctr2W, edgeW,
                                        wIn2, wSeg2, wMeta, wCtr, wCtr2, wEdge,
                                        nodes, out);

    // encoders
    k_in<<<gRows, blk, 0, stream>>>(nodes, in1W, in1b, wIn2, ing, inbg,
                                    seg1W, seg1b, wSeg2, segg, segbg, preB);
    k_meta<<<gRows, blk, 0, stream>>>(preB, nodes, wMeta, metag, metabg, featB0);

    // 4 rounds; last round writes d_out directly
    bf16* bufs[2] = { featB0, featB1 };
    for (int i = 0; i < 4; ++i) {
        k_round<<<gRows, dim3(512), 0, stream>>>(bufs[i & 1], ptr, (const int*)elist,
                                                 wEdge + (size_t)i * 14 * 16384,
                                                 wCtr + (size_t)i * 16384,
                                                 wCtr2 + (size_t)i * 16384,
                                                 normg + i * 128, normbg + i * 128,
                                                 ctr2g + i * 128, ctr2bg + i * 128,
                                                 bufs[(i + 1) & 1], out,
                                                 i == 3 ? 1 : 0);
    }
}

// Round 11
// 1509.841 us; speedup vs baseline: 1.0239x; 1.0239x over previous
//
#include <hip/hip_runtime.h>
#include <hip/hip_bf16.h>

#define NN 100000
#define NE 100000
#define NCNT (14 * NN)
#define LP 136    // padded LDS pitch (bf16) for encoder kernels
#define LP2 168   // pitch for K=160 (meta)
#define SCAN_CHUNK 4096
#define NSCB ((NCNT + SCAN_CHUNK - 1) / SCAN_CHUNK)

typedef __bf16 bf16;
typedef __bf16 bf16x8 __attribute__((ext_vector_type(8)));
typedef float  f32x4  __attribute__((ext_vector_type(4)));
typedef unsigned long long u64;

// ---------- generic helpers ----------

__device__ __forceinline__ void zacc8(f32x4 acc[8]) {
    f32x4 z = {0.f, 0.f, 0.f, 0.f};
#pragma unroll
    for (int n = 0; n < 8; ++n) acc[n] = z;
}

// per-wave GroupNorm(1) stats (encoder kernels): wave holds 16 full rows
__device__ __forceinline__ void gnstats(const f32x4 acc[8], float mean[4], float rs[4]) {
    float s1[4], s2[4];
#pragma unroll
    for (int r = 0; r < 4; ++r) { s1[r] = 0.f; s2[r] = 0.f; }
#pragma unroll
    for (int n = 0; n < 8; ++n)
#pragma unroll
        for (int r = 0; r < 4; ++r) { float v = acc[n][r]; s1[r] += v; s2[r] += v * v; }
#pragma unroll
    for (int off = 1; off < 16; off <<= 1) {
#pragma unroll
        for (int r = 0; r < 4; ++r) {
            s1[r] += __shfl_xor(s1[r], off, 64);
            s2[r] += __shfl_xor(s2[r], off, 64);
        }
    }
#pragma unroll
    for (int r = 0; r < 4; ++r) {
        const float m = s1[r] * 0.0078125f;
        const float v = fmaxf(s2[r] * 0.0078125f - m * m, 0.f);
        mean[r] = m;
        rs[r] = rsqrtf(v + 1e-5f);
    }
}

// ---------- encoder-path helpers ----------

template<int PITCH, int COLS>
__device__ inline void stageWB(const bf16* __restrict__ Wg, bf16* Wl) {
    constexpr int NV = 128 * COLS / 8;
    for (int i = threadIdx.x; i < NV; i += 256) {
        const int e = i * 8;
        const int r = e / COLS, c = e % COLS;
        *(float4*)(&Wl[r * PITCH + c]) = ((const float4*)Wg)[i];
    }
}

template<int PITCH, int KSTEPS>
__device__ inline void mmaT(const bf16* Al, const bf16* Wl, int m0, int lane, f32x4 acc[8]) {
#pragma unroll
    for (int kk = 0; kk < KSTEPS; ++kk) {
        bf16x8 a = *(const bf16x8*)(&Al[(m0 + (lane & 15)) * PITCH + kk * 32 + (lane >> 4) * 8]);
#pragma unroll
        for (int n = 0; n < 8; ++n) {
            bf16x8 b = *(const bf16x8*)(&Wl[(n * 16 + (lane & 15)) * PITCH + kk * 32 + (lane >> 4) * 8]);
            acc[n] = __builtin_amdgcn_mfma_f32_16x16x32_bf16(a, b, acc[n], 0, 0, 0);
        }
    }
}

// ---------- weight conversion + nodes output slice (one kernel) ----------

__global__ __launch_bounds__(256) void k_cvt_all(
    const float* __restrict__ in2W, const float* __restrict__ seg2W,
    const float* __restrict__ metaW, const float* __restrict__ ctrW,
    const float* __restrict__ ctr2W, const float* __restrict__ edgeW,
    bf16* __restrict__ wIn2, bf16* __restrict__ wSeg2, bf16* __restrict__ wMeta,
    bf16* __restrict__ wCtr, bf16* __restrict__ wCtr2, bf16* __restrict__ wEdge,
    const float* __restrict__ nodes, float* __restrict__ outp)
{
    for (int j = blockIdx.x * 256 + threadIdx.x; j < 2 * NN; j += gridDim.x * 256)
        outp[(size_t)NN * 128 + j] = nodes[(size_t)(j >> 1) * 8 + (j & 1)];
    const int total = 16384 + 16384 + 20480 + 65536 + 65536 + 917504;
    for (int i = blockIdx.x * 256 + threadIdx.x; i < total; i += gridDim.x * 256) {
        int j = i;
        if (j < 16384) { wIn2[j] = (bf16)in2W[j]; continue; }
        j -= 16384;
        if (j < 16384) { wSeg2[j] = (bf16)seg2W[j]; continue; }
        j -= 16384;
        if (j < 20480) {
            const int r = j / 160, c = j % 160;
            wMeta[j] = (bf16)(c < 132 ? metaW[r * 132 + c] : 0.f);
            continue;
        }
        j -= 20480;
        if (j < 65536) { wCtr[j] = (bf16)ctrW[j]; continue; }
        j -= 65536;
        if (j < 65536) { wCtr2[j] = (bf16)ctr2W[j]; continue; }
        j -= 65536;
        wEdge[j] = (bf16)edgeW[j];
    }
}

// ---------- CSR build ----------

__global__ __launch_bounds__(256) void k_count(const int* __restrict__ idx,
                                               const int* __restrict__ mask,
                                               int* __restrict__ cnt) {
    __shared__ int lim[14];
    if (threadIdx.x < 14) lim[threadIdx.x] = min(mask[threadIdx.x], NE);
    __syncthreads();
    for (int i = blockIdx.x * 256 + threadIdx.x; i < 14 * NE; i += gridDim.x * 256) {
        const int e = i / 14, t = i - e * 14;
        if (e < lim[t]) atomicAdd(&cnt[t * NN + idx[(size_t)e * 28 + 2 * t]], 1);
    }
}

__global__ __launch_bounds__(256) void k_scanA(const int* __restrict__ cnt,
                                               int* __restrict__ ptr,
                                               int* __restrict__ tot) {
    __shared__ int sm[256];
    const int tid = threadIdx.x;
    const int base = blockIdx.x * SCAN_CHUNK + tid * 16;
    int v[16]; int run = 0;
#pragma unroll
    for (int j = 0; j < 16; ++j) {
        const int x = (base + j < NCNT) ? cnt[base + j] : 0;
        v[j] = run; run += x;
    }
    sm[tid] = run; __syncthreads();
    for (int d = 1; d < 256; d <<= 1) {
        int t = 0;
        if (tid >= d) t = sm[tid - d];
        __syncthreads();
        sm[tid] += t;
        __syncthreads();
    }
    const int off = sm[tid] - run;
#pragma unroll
    for (int j = 0; j < 16; ++j)
        if (base + j < NCNT) ptr[base + j] = v[j] + off;
    if (tid == 255) tot[blockIdx.x] = sm[255];
}

// scanC with block-prefix computed in-kernel (scanB folded in)
__global__ __launch_bounds__(256) void k_scanC(int* __restrict__ ptr,
                                               int* __restrict__ cursor,
                                               const int* __restrict__ tot) {
    __shared__ int off_s;
    if (threadIdx.x == 0) {
        int acc = 0;
        for (int b = 0; b < blockIdx.x; ++b) acc += tot[b];
        off_s = acc;
    }
    __syncthreads();
    const int base = blockIdx.x * SCAN_CHUNK;
    const int o = off_s;
    for (int j = threadIdx.x; j < SCAN_CHUNK; j += 256) {
        const int i = base + j;
        if (i < NCNT) { const int p = ptr[i] + o; ptr[i] = p; cursor[i] = p; }
    }
    if (blockIdx.x == 0 && threadIdx.x == 0) {
        int acc = 0;
        for (int b = 0; b < NSCB; ++b) acc += tot[b];
        ptr[NCNT] = acc;
    }
}

// elist entry: (edge_id << 32) | src
__global__ __launch_bounds__(256) void k_fill(const int* __restrict__ idx,
                                              const int* __restrict__ mask,
                                              int* __restrict__ cursor,
                                              u64* __restrict__ el) {
    __shared__ int lim[14];
    if (threadIdx.x < 14) lim[threadIdx.x] = min(mask[threadIdx.x], NE);
    __syncthreads();
    for (int i = blockIdx.x * 256 + threadIdx.x; i < 14 * NE; i += gridDim.x * 256) {
        const int e = i / 14, t = i - e * 14;
        if (e < lim[t]) {
            const int dst = idx[(size_t)e * 28 + 2 * t];
            const int src = idx[(size_t)e * 28 + 2 * t + 1];
            const int pos = atomicAdd(&cursor[t * NN + dst], 1);
            el[pos] = ((u64)(unsigned)e << 32) | (unsigned)src;
        }
    }
}

__global__ __launch_bounds__(256) void k_sortseg(const int* __restrict__ ptr,
                                                 u64* __restrict__ el) {
    for (int i = blockIdx.x * 256 + threadIdx.x; i < NCNT; i += gridDim.x * 256) {
        const int s = ptr[i], e2 = ptr[i + 1];
        for (int a = s + 1; a < e2; ++a) {
            const u64 key = el[a];
            int b = a - 1;
            while (b >= s && el[b] > key) { el[b + 1] = el[b]; --b; }
            el[b + 1] = key;
        }
    }
}

// ---------- input encoder ----------

__global__ __launch_bounds__(256) void k_in(
    const float* __restrict__ nodes,
    const float* __restrict__ in1W, const float* __restrict__ in1b,
    const bf16* __restrict__ wIn2,
    const float* __restrict__ ing, const float* __restrict__ inbg,
    const float* __restrict__ seg1W, const float* __restrict__ seg1b,
    const bf16* __restrict__ wSeg2,
    const float* __restrict__ segg, const float* __restrict__ segbg,
    bf16* __restrict__ outPre)
{
    __shared__ __align__(16) bf16 Wl[128 * LP];
    __shared__ __align__(16) bf16 Al[64 * LP];
    __shared__ float w0[128], w1[128], bb[128];
    __shared__ float xs[64][4];
    const int tid = threadIdx.x;
    const int row0 = blockIdx.x * 64;
    if (tid < 64) {
        const int row = row0 + tid;
        float4 x = {0.f, 0.f, 0.f, 0.f};
        if (row < NN) x = *(const float4*)(nodes + (size_t)row * 8);
        xs[tid][0] = x.x; xs[tid][1] = x.y; xs[tid][2] = x.z; xs[tid][3] = x.w;
    }
    if (tid < 128) { w0[tid] = in1W[tid * 2]; w1[tid] = in1W[tid * 2 + 1]; bb[tid] = in1b[tid]; }
    stageWB<LP, 128>(wIn2, Wl);
    __syncthreads();
    for (int i = tid; i < 64 * 128; i += 256) {
        const int r = i >> 7, j = i & 127;
        Al[r * LP + j] = (bf16)fmaxf(xs[r][0] * w0[j] + xs[r][1] * w1[j] + bb[j], 0.f);
    }
    __syncthreads();
    const int lane = tid & 63, m0 = (tid >> 6) * 16;
    f32x4 accP[8]; zacc8(accP);
    mmaT<LP, 4>(Al, Wl, m0, lane, accP);
    __syncthreads();
    if (tid < 128) { w0[tid] = seg1W[tid * 2]; w1[tid] = seg1W[tid * 2 + 1]; bb[tid] = seg1b[tid]; }
    stageWB<LP, 128>(wSeg2, Wl);
    __syncthreads();
    for (int i = tid; i < 64 * 128; i += 256) {
        const int r = i >> 7, j = i & 127;
        Al[r * LP + j] = (bf16)fmaxf(xs[r][2] * w0[j] + xs[r][3] * w1[j] + bb[j], 0.f);
    }
    __syncthreads();
    f32x4 accQ[8]; zacc8(accQ);
    mmaT<LP, 4>(Al, Wl, m0, lane, accQ);

    float mP[4], rP[4], mQ[4], rQ[4];
    gnstats(accP, mP, rP);
    gnstats(accQ, mQ, rQ);
    float gP[8], bP[8], gQ[8], bQ[8];
#pragma unroll
    for (int n = 0; n < 8; ++n) {
        const int c = n * 16 + (lane & 15);
        gP[n] = ing[c]; bP[n] = inbg[c]; gQ[n] = segg[c]; bQ[n] = segbg[c];
    }
#pragma unroll
    for (int r = 0; r < 4; ++r) {
        const int row = row0 + m0 + (lane >> 4) * 4 + r;
        if (row < NN) {
#pragma unroll
            for (int n = 0; n < 8; ++n) {
                const float yp = (accP[n][r] - mP[r]) * rP[r] * gP[n] + bP[n];
                const float yq = (accQ[n][r] - mQ[r]) * rQ[r] * gQ[n] + bQ[n];
                outPre[(size_t)row * 128 + n * 16 + (lane & 15)] = (bf16)fmaxf(yp + yq, 0.f);
            }
        }
    }
}

// ---------- meta ----------

__global__ __launch_bounds__(256) void k_meta(
    const bf16* __restrict__ Apre, const float* __restrict__ nodes,
    const bf16* __restrict__ Wg,
    const float* __restrict__ g, const float* __restrict__ bg,
    bf16* __restrict__ featB)
{
    __shared__ __align__(16) bf16 Wl[128 * LP2];
    __shared__ __align__(16) bf16 Al[64 * LP2];
    const int row0 = blockIdx.x * 64;
    stageWB<LP2, 160>(Wg, Wl);
    {
        const int r = threadIdx.x >> 2, q = threadIdx.x & 3;
        float4* d = (float4*)(&Al[r * LP2 + q * 32]);
        const int row = row0 + r;
        if (row < NN) {
            const float4* s = (const float4*)(Apre + (size_t)row * 128 + q * 32);
            float4 a0 = s[0], a1 = s[1], a2 = s[2], a3 = s[3];
            d[0] = a0; d[1] = a1; d[2] = a2; d[3] = a3;
        } else {
            float4 z = {0.f, 0.f, 0.f, 0.f};
            d[0] = z; d[1] = z; d[2] = z; d[3] = z;
        }
    }
    if (threadIdx.x < 64) {
        const int rr = threadIdx.x, row = row0 + rr;
        bf16* d = &Al[rr * LP2 + 128];
        if (row < NN) {
            const float4 x = *(const float4*)(nodes + (size_t)row * 8 + 4);
            d[0] = (bf16)x.x; d[1] = (bf16)x.y; d[2] = (bf16)x.z; d[3] = (bf16)x.w;
        } else {
            d[0] = (bf16)0.f; d[1] = (bf16)0.f; d[2] = (bf16)0.f; d[3] = (bf16)0.f;
        }
#pragma unroll
        for (int c = 4; c < 32; ++c) d[c] = (bf16)0.f;
    }
    __syncthreads();
    const int lane = threadIdx.x & 63, m0 = (threadIdx.x >> 6) * 16;
    f32x4 acc[8]; zacc8(acc);
    mmaT<LP2, 5>(Al, Wl, m0, lane, acc);

    float mean[4], rs[4];
    gnstats(acc, mean, rs);
    float gv[8], bv[8];
#pragma unroll
    for (int n = 0; n < 8; ++n) { const int c = n * 16 + (lane & 15); gv[n] = g[c]; bv[n] = bg[c]; }
#pragma unroll
    for (int r = 0; r < 4; ++r) {
        const int row = row0 + m0 + (lane >> 4) * 4 + r;
        if (row < NN) {
            const size_t off = (size_t)row * 128 + (lane & 15);
#pragma unroll
            for (int n = 0; n < 8; ++n) {
                const float y = (acc[n][r] - mean[r]) * rs[r] * gv[n] + bv[n];
                featB[off + n * 16] = (bf16)fmaxf(y, 0.f);
            }
        }
    }
}

// ---------- fused round: TWO edge types per phase (7 phases + ctr + ctr2) ----------
// M=64/block, 512 threads = 8 waves; wave w owns output cols w*16..w*16+15.
// Per phase u: MFMA types {2u,2u+1} from two LDS tiles; gather types {2u+2,2u+3}
// (heads issued post-barrier, r9 discipline). Halves barrier/phase count vs r9.

__global__ __launch_bounds__(512, 2) void k_round(
    const bf16* __restrict__ feat,
    const int* __restrict__ ptr,
    const int* __restrict__ sl32,      // u64 elist as int pairs; src = sl32[2*j]
    const bf16* __restrict__ wEdgeR,   // 14 * 16384
    const bf16* __restrict__ wCtrR,
    const bf16* __restrict__ wCtr2R,
    const float* __restrict__ ng, const float* __restrict__ nbg,
    const float* __restrict__ c2g, const float* __restrict__ c2bg,
    bf16* __restrict__ featOut,
    float* __restrict__ outF,
    int last)
{
    __shared__ __align__(16) bf16 AT[2][2][64 * 128];  // [dbuf][type-slot] 16KB tiles
    __shared__ float red[8 * 64 * 2];
    __shared__ float stats[64 * 2];

    const int tid = threadIdx.x;
    const int w = tid >> 6, lane = tid & 63;
    const int r = lane & 15, h = lane >> 4, r7 = r & 7;
    const int n0 = w * 16;
    const int row0 = blockIdx.x * 64;

    // gather role: 8 threads per row, 32B slice each
    const int rr = tid >> 3, sl = tid & 7;
    const int grow = row0 + rr;
    const bool rowok = grow < NN;
    const int wb0 = rr * 256 + (((2 * sl)     ^ (rr & 7)) * 16);
    const int wb1 = rr * 256 + (((2 * sl + 1) ^ (rr & 7)) * 16);

    const char* fb = (const char*)feat;

    // ---- CSR state for the pair of types being gathered next ----
    int pA0 = 0, pA1 = 0, pB0 = 0, pB1 = 0;      // segments (even, odd)
    int sA0 = 0, sA1 = 0, sB0 = 0, sB1 = 0;      // head srcs
    int npA0 = 0, npA1 = 0, npB0 = 0, npB1 = 0;  // ptr for pair after

    float agA[16], agB[16];

    // ---- preloop: gather types 0,1 (latency exposed once) ----
    {
        int q0A = 0, q1A = 0, q0B = 0, q1B = 0;
        if (rowok) {
            q0A = ptr[grow];      q1A = ptr[grow + 1];
            q0B = ptr[NN + grow]; q1B = ptr[NN + grow + 1];
        }
        int h0A = 0, h1A = 0, h0B = 0, h1B = 0;
        if (q1A > q0A)     h0A = sl32[2 * q0A];
        if (q1A > q0A + 1) h1A = sl32[2 * (q0A + 1)];
        if (q1B > q0B)     h0B = sl32[2 * q0B];
        if (q1B > q0B + 1) h1B = sl32[2 * (q0B + 1)];
        // prefetch state for types 2,3 and ptr for 4,5
        if (rowok) {
            pA0 = ptr[2 * NN + grow]; pA1 = ptr[2 * NN + grow + 1];
            pB0 = ptr[3 * NN + grow]; pB1 = ptr[3 * NN + grow + 1];
            npA0 = ptr[4 * NN + grow]; npA1 = ptr[4 * NN + grow + 1];
            npB0 = ptr[5 * NN + grow]; npB1 = ptr[5 * NN + grow + 1];
        }
        if (pA1 > pA0)     sA0 = sl32[2 * pA0];
        if (pA1 > pA0 + 1) sA1 = sl32[2 * (pA0 + 1)];
        if (pB1 > pB0)     sB0 = sl32[2 * pB0];
        if (pB1 > pB0 + 1) sB1 = sl32[2 * (pB0 + 1)];

        bf16x8 e0, e1;
#pragma unroll
        for (int j = 0; j < 16; ++j) { agA[j] = 0.f; agB[j] = 0.f; }
        const int dA = q1A - q0A, dB = q1B - q0B;
        if (dA > 0) { const bf16x8* q = (const bf16x8*)(fb + (size_t)h0A * 256 + sl * 32); e0 = q[0]; e1 = q[1];
#pragma unroll
            for (int j = 0; j < 8; ++j) { agA[j] += (float)e0[j]; agA[8 + j] += (float)e1[j]; } }
        if (dA > 1) { const bf16x8* q = (const bf16x8*)(fb + (size_t)h1A * 256 + sl * 32); e0 = q[0]; e1 = q[1];
#pragma unroll
            for (int j = 0; j < 8; ++j) { agA[j] += (float)e0[j]; agA[8 + j] += (float)e1[j]; } }
        for (int j2 = q0A + 2; j2 < q1A; ++j2) {
            const bf16x8* q = (const bf16x8*)(fb + (size_t)sl32[2 * j2] * 256 + sl * 32); e0 = q[0]; e1 = q[1];
#pragma unroll
            for (int j = 0; j < 8; ++j) { agA[j] += (float)e0[j]; agA[8 + j] += (float)e1[j]; }
        }
        if (dB > 0) { const bf16x8* q = (const bf16x8*)(fb + (size_t)h0B * 256 + sl * 32); e0 = q[0]; e1 = q[1];
#pragma unroll
            for (int j = 0; j < 8; ++j) { agB[j] += (float)e0[j]; agB[8 + j] += (float)e1[j]; } }
        if (dB > 1) { const bf16x8* q = (const bf16x8*)(fb + (size_t)h1B * 256 + sl * 32); e0 = q[0]; e1 = q[1];
#pragma unroll
            for (int j = 0; j < 8; ++j) { agB[j] += (float)e0[j]; agB[8 + j] += (float)e1[j]; } }
        for (int j2 = q0B + 2; j2 < q1B; ++j2) {
            const bf16x8* q = (const bf16x8*)(fb + (size_t)sl32[2 * j2] * 256 + sl * 32); e0 = q[0]; e1 = q[1];
#pragma unroll
            for (int j = 0; j < 8; ++j) { agB[j] += (float)e0[j]; agB[8 + j] += (float)e1[j]; }
        }
    }

    f32x4 acc[4];
    { f32x4 z = {0.f, 0.f, 0.f, 0.f}; acc[0] = z; acc[1] = z; acc[2] = z; acc[3] = z; }

    for (int u = 0; u < 7; ++u) {
        // write agA, agB (types 2u, 2u+1) into buffer (u&1)
        {
            bf16x8 av0, av1;
            char* atbA = (char*)AT[u & 1][0];
            char* atbB = (char*)AT[u & 1][1];
#pragma unroll
            for (int j = 0; j < 8; ++j) { av0[j] = (bf16)agA[j]; av1[j] = (bf16)agA[8 + j]; }
            *(bf16x8*)(atbA + wb0) = av0;
            *(bf16x8*)(atbA + wb1) = av1;
#pragma unroll
            for (int j = 0; j < 8; ++j) { av0[j] = (bf16)agB[j]; av1[j] = (bf16)agB[8 + j]; }
            *(bf16x8*)(atbB + wb0) = av0;
            *(bf16x8*)(atbB + wb1) = av1;
        }
        // B fragments for type 2u (pre-barrier; latency hides under barrier wait)
        const bf16* WtA = wEdgeR + (size_t)(2 * u) * 16384;
        bf16x8 bfrA[4];
#pragma unroll
        for (int kk = 0; kk < 4; ++kk)
            bfrA[kk] = *(const bf16x8*)(WtA + (n0 + r) * 128 + kk * 32 + h * 8);

        asm volatile("s_waitcnt lgkmcnt(0)" ::: "memory");
        __builtin_amdgcn_s_barrier();
        __builtin_amdgcn_sched_barrier(0);

        // B fragments for type 2u+1 (latency hides under MFMA-A)
        const bf16* WtB = wEdgeR + (size_t)(2 * u + 1) * 16384;
        bf16x8 bfrB[4];
#pragma unroll
        for (int kk = 0; kk < 4; ++kk)
            bfrB[kk] = *(const bf16x8*)(WtB + (n0 + r) * 128 + kk * 32 + h * 8);

        // issue next-pair gather heads + index prefetch (r9 discipline: post-barrier)
        bf16x8 eA00, eA01, eA10, eA11, eB00, eB01, eB10, eB11;
        int dA = 0, dB = 0;
        int uA0 = 0, uA1 = 0, uB0 = 0, uB1 = 0;
        int qA0 = 0, qA1 = 0, qB0 = 0, qB1 = 0;
        if (u < 6) {
            dA = pA1 - pA0; dB = pB1 - pB0;
            if (dA > 0) { const bf16x8* q = (const bf16x8*)(fb + (size_t)sA0 * 256 + sl * 32); eA00 = q[0]; eA01 = q[1]; }
            if (dA > 1) { const bf16x8* q = (const bf16x8*)(fb + (size_t)sA1 * 256 + sl * 32); eA10 = q[0]; eA11 = q[1]; }
            if (dB > 0) { const bf16x8* q = (const bf16x8*)(fb + (size_t)sB0 * 256 + sl * 32); eB00 = q[0]; eB01 = q[1]; }
            if (dB > 1) { const bf16x8* q = (const bf16x8*)(fb + (size_t)sB1 * 256 + sl * 32); eB10 = q[0]; eB11 = q[1]; }
            if (u <= 4) {  // heads for types 2u+4, 2u+5 from np
                const int dnA = npA1 - npA0, dnB = npB1 - npB0;
                if (dnA > 0) uA0 = sl32[2 * npA0];
                if (dnA > 1) uA1 = sl32[2 * (npA0 + 1)];
                if (dnB > 0) uB0 = sl32[2 * npB0];
                if (dnB > 1) uB1 = sl32[2 * (npB0 + 1)];
            }
            if (u <= 3 && rowok) {  // ptr for types 2u+6, 2u+7
                const size_t bA = (size_t)(2 * u + 6) * NN + grow;
                const size_t bB = (size_t)(2 * u + 7) * NN + grow;
                qA0 = ptr[bA]; qA1 = ptr[bA + 1];
                qB0 = ptr[bB]; qB1 = ptr[bB + 1];
            }
        } else {
            // u == 6: gather ctr self row into agA path
            if (rowok) { const bf16x8* q = (const bf16x8*)(fb + (size_t)grow * 256 + sl * 32); eA00 = q[0]; eA01 = q[1]; dA = 1; }
        }

        // MFMA type 2u then 2u+1
        {
            const char* atrA = (const char*)AT[u & 1][0];
            const char* atrB = (const char*)AT[u & 1][1];
#pragma unroll
            for (int m = 0; m < 4; ++m) {
                const int arow = m * 16 + r;
#pragma unroll
                for (int kk = 0; kk < 4; ++kk) {
                    const bf16x8 a = *(const bf16x8*)(atrA + arow * 256 + (((kk * 4 + h) ^ r7) * 16));
                    acc[m] = __builtin_amdgcn_mfma_f32_16x16x32_bf16(a, bfrA[kk], acc[m], 0, 0, 0);
                }
            }
#pragma unroll
            for (int m = 0; m < 4; ++m) {
                const int arow = m * 16 + r;
#pragma unroll
                for (int kk = 0; kk < 4; ++kk) {
                    const bf16x8 a = *(const bf16x8*)(atrB + arow * 256 + (((kk * 4 + h) ^ r7) * 16));
                    acc[m] = __builtin_amdgcn_mfma_f32_16x16x32_bf16(a, bfrB[kk], acc[m], 0, 0, 0);
                }
            }
        }

        // finish gathers for next pair (heads + rare serial tails)
#pragma unroll
        for (int j = 0; j < 16; ++j) { agA[j] = 0.f; agB[j] = 0.f; }
        if (u < 6) {
            if (dA > 0) {
#pragma unroll
                for (int j = 0; j < 8; ++j) { agA[j] += (float)eA00[j]; agA[8 + j] += (float)eA01[j]; }
            }
            if (dA > 1) {
#pragma unroll
                for (int j = 0; j < 8; ++j) { agA[j] += (float)eA10[j]; agA[8 + j] += (float)eA11[j]; }
            }
            for (int j2 = pA0 + 2; j2 < pA1; ++j2) {
                const bf16x8* q = (const bf16x8*)(fb + (size_t)sl32[2 * j2] * 256 + sl * 32);
                const bf16x8 e0 = q[0], e1 = q[1];
#pragma unroll
                for (int j = 0; j < 8; ++j) { agA[j] += (float)e0[j]; agA[8 + j] += (float)e1[j]; }
            }
            if (dB > 0) {
#pragma unroll
                for (int j = 0; j < 8; ++j) { agB[j] += (float)eB00[j]; agB[8 + j] += (float)eB01[j]; }
            }
            if (dB > 1) {
#pragma unroll
                for (int j = 0; j < 8; ++j) { agB[j] += (float)eB10[j]; agB[8 + j] += (float)eB11[j]; }
            }
            for (int j2 = pB0 + 2; j2 < pB1; ++j2) {
                const bf16x8* q = (const bf16x8*)(fb + (size_t)sl32[2 * j2] * 256 + sl * 32);
                const bf16x8 e0 = q[0], e1 = q[1];
#pragma unroll
                for (int j = 0; j < 8; ++j) { agB[j] += (float)e0[j]; agB[8 + j] += (float)e1[j]; }
            }
            // rotate state
            pA0 = npA0; pA1 = npA1; pB0 = npB0; pB1 = npB1;
            sA0 = uA0; sA1 = uA1; sB0 = uB0; sB1 = uB1;
            npA0 = qA0; npA1 = qA1; npB0 = qB0; npB1 = qB1;
        } else if (dA > 0) {  // u == 6: ctr row
#pragma unroll
            for (int j = 0; j < 8; ++j) { agA[j] += (float)eA00[j]; agA[8 + j] += (float)eA01[j]; }
        }
    }

    // ---- ctr phase: agA = self feat row; buffer 1 (phase 6 used buffer 0) ----
    {
        bf16x8 av0, av1;
#pragma unroll
        for (int j = 0; j < 8; ++j) { av0[j] = (bf16)agA[j]; av1[j] = (bf16)agA[8 + j]; }
        char* atb = (char*)AT[1][0];
        *(bf16x8*)(atb + wb0) = av0;
        *(bf16x8*)(atb + wb1) = av1;
        bf16x8 bfrC[4];
#pragma unroll
        for (int kk = 0; kk < 4; ++kk)
            bfrC[kk] = *(const bf16x8*)(wCtrR + (n0 + r) * 128 + kk * 32 + h * 8);
        asm volatile("s_waitcnt lgkmcnt(0)" ::: "memory");
        __builtin_amdgcn_s_barrier();
        __builtin_amdgcn_sched_barrier(0);
        const char* atr = (const char*)AT[1][0];
#pragma unroll
        for (int m = 0; m < 4; ++m) {
            const int arow = m * 16 + r;
#pragma unroll
            for (int kk = 0; kk < 4; ++kk) {
                const bf16x8 a = *(const bf16x8*)(atr + arow * 256 + (((kk * 4 + h) ^ r7) * 16));
                acc[m] = __builtin_amdgcn_mfma_f32_16x16x32_bf16(a, bfrC[kk], acc[m], 0, 0, 0);
            }
        }
    }

    // ---- GN 1: cross-wave reduction ----
#pragma unroll
    for (int m = 0; m < 4; ++m) {
        float a1[4], a2[4];
#pragma unroll
        for (int g2 = 0; g2 < 4; ++g2) { const float v = acc[m][g2]; a1[g2] = v; a2[g2] = v * v; }
#pragma unroll
        for (int off = 1; off < 16; off <<= 1)
#pragma unroll
            for (int g2 = 0; g2 < 4; ++g2) {
                a1[g2] += __shfl_xor(a1[g2], off, 64);
                a2[g2] += __shfl_xor(a2[g2], off, 64);
            }
        if (r == 0) {
#pragma unroll
            for (int g2 = 0; g2 < 4; ++g2) {
                const int row = m * 16 + h * 4 + g2;
                red[(w * 64 + row) * 2]     = a1[g2];
                red[(w * 64 + row) * 2 + 1] = a2[g2];
            }
        }
    }
    __syncthreads();
    if (tid < 64) {
        float s1 = 0.f, s2 = 0.f;
#pragma unroll
        for (int ww = 0; ww < 8; ++ww) { s1 += red[(ww * 64 + tid) * 2]; s2 += red[(ww * 64 + tid) * 2 + 1]; }
        const float mn = s1 * 0.0078125f;
        const float vr = fmaxf(s2 * 0.0078125f - mn * mn, 0.f);
        stats[tid * 2]     = mn;
        stats[tid * 2 + 1] = rsqrtf(vr + 1e-5f);
    }
    __syncthreads();

    // epilogue 1: y = relu(gn(acc)) -> AT[0][0] (swizzled); load ctr2 B
    const float gv1 = ng[n0 + r], bv1 = nbg[n0 + r];
    bf16x8 bfr2[4];
#pragma unroll
    for (int kk = 0; kk < 4; ++kk)
        bfr2[kk] = *(const bf16x8*)(wCtr2R + (n0 + r) * 128 + kk * 32 + h * 8);
    {
        char* atb = (char*)AT[0][0];
        const int colb = (n0 + r) * 2;
#pragma unroll
        for (int m = 0; m < 4; ++m)
#pragma unroll
            for (int g2 = 0; g2 < 4; ++g2) {
                const int row = m * 16 + h * 4 + g2;
                const float y = (acc[m][g2] - stats[row * 2]) * stats[row * 2 + 1] * gv1 + bv1;
                const int slot = (colb >> 4) ^ (row & 7);
                *(bf16*)(atb + row * 256 + slot * 16 + (colb & 15)) = (bf16)fmaxf(y, 0.f);
            }
    }
    __syncthreads();

    // ctr2 GEMM
    f32x4 ac2[4];
    { f32x4 z = {0.f, 0.f, 0.f, 0.f}; ac2[0] = z; ac2[1] = z; ac2[2] = z; ac2[3] = z; }
    {
        const char* atr = (const char*)AT[0][0];
#pragma unroll
        for (int m = 0; m < 4; ++m) {
            const int arow = m * 16 + r;
#pragma unroll
            for (int kk = 0; kk < 4; ++kk) {
                const bf16x8 a = *(const bf16x8*)(atr + arow * 256 + (((kk * 4 + h) ^ r7) * 16));
                ac2[m] = __builtin_amdgcn_mfma_f32_16x16x32_bf16(a, bfr2[kk], ac2[m], 0, 0, 0);
            }
        }
    }

    // ---- GN 2 ----
#pragma unroll
    for (int m = 0; m < 4; ++m) {
        float a1[4], a2[4];
#pragma unroll
        for (int g2 = 0; g2 < 4; ++g2) { const float v = ac2[m][g2]; a1[g2] = v; a2[g2] = v * v; }
#pragma unroll
        for (int off = 1; off < 16; off <<= 1)
#pragma unroll
            for (int g2 = 0; g2 < 4; ++g2) {
                a1[g2] += __shfl_xor(a1[g2], off, 64);
                a2[g2] += __shfl_xor(a2[g2], off, 64);
            }
        if (r == 0) {
#pragma unroll
            for (int g2 = 0; g2 < 4; ++g2) {
                const int row = m * 16 + h * 4 + g2;
                red[(w * 64 + row) * 2]     = a1[g2];
                red[(w * 64 + row) * 2 + 1] = a2[g2];
            }
        }
    }
    __syncthreads();
    if (tid < 64) {
        float s1 = 0.f, s2 = 0.f;
#pragma unroll
        for (int ww = 0; ww < 8; ++ww) { s1 += red[(ww * 64 + tid) * 2]; s2 += red[(ww * 64 + tid) * 2 + 1]; }
        const float mn = s1 * 0.0078125f;
        const float vr = fmaxf(s2 * 0.0078125f - mn * mn, 0.f);
        stats[tid * 2]     = mn;
        stats[tid * 2 + 1] = rsqrtf(vr + 1e-5f);
    }
    __syncthreads();

    // epilogue 2: o = relu(gn(ac2) + feat)
    const float gv2 = c2g[n0 + r], bv2 = c2bg[n0 + r];
#pragma unroll
    for (int m = 0; m < 4; ++m)
#pragma unroll
        for (int g2 = 0; g2 < 4; ++g2) {
            const int row = m * 16 + h * 4 + g2;
            const int orow = row0 + row;
            if (orow < NN) {
                const size_t off = (size_t)orow * 128 + n0 + r;
                const float y = (ac2[m][g2] - stats[row * 2]) * stats[row * 2 + 1] * gv2 + bv2;
                const float o = fmaxf(y + (float)feat[off], 0.f);
                if (last) outF[off] = o;
                else      featOut[off] = (bf16)o;
            }
        }
}

// ---------- launch ----------

extern "C" void kernel_launch(void* const* d_in, const int* in_sizes, int n_in,
                              void* d_out, int out_size, void* d_ws, size_t ws_size,
                              hipStream_t stream) {
    const float* nodes  = (const float*)d_in[0];
    const int*   idx    = (const int*)d_in[1];
    const int*   mask   = (const int*)d_in[2];
    const float* in1W   = (const float*)d_in[3];
    const float* in1b   = (const float*)d_in[4];
    const float* in2W   = (const float*)d_in[5];
    const float* ing    = (const float*)d_in[6];
    const float* inbg   = (const float*)d_in[7];
    const float* seg1W  = (const float*)d_in[8];
    const float* seg1b  = (const float*)d_in[9];
    const float* seg2W  = (const float*)d_in[10];
    const float* segg   = (const float*)d_in[11];
    const float* segbg  = (const float*)d_in[12];
    const float* metaW  = (const float*)d_in[13];
    const float* metag  = (const float*)d_in[14];
    const float* metabg = (const float*)d_in[15];
    const float* ctrW   = (const float*)d_in[16];
    const float* edgeW  = (const float*)d_in[17];
    const float* normg  = (const float*)d_in[18];
    const float* normbg = (const float*)d_in[19];
    const float* ctr2W  = (const float*)d_in[20];
    const float* ctr2g  = (const float*)d_in[21];
    const float* ctr2bg = (const float*)d_in[22];
    float* out = (float*)d_out;

    char* w = (char*)d_ws;
    bf16*  featB0 = (bf16*)w;  w += (size_t)NN * 128 * 2;
    bf16*  featB1 = (bf16*)w;  w += (size_t)NN * 128 * 2;
    bf16*  preB   = (bf16*)w;  w += (size_t)NN * 128 * 2;
    bf16*  wIn2   = (bf16*)w;  w += 16384 * 2;
    bf16*  wSeg2  = (bf16*)w;  w += 16384 * 2;
    bf16*  wMeta  = (bf16*)w;  w += 20480 * 2;
    bf16*  wCtr   = (bf16*)w;  w += 65536 * 2;
    bf16*  wCtr2  = (bf16*)w;  w += 65536 * 2;
    bf16*  wEdge  = (bf16*)w;  w += (size_t)917504 * 2;
    int*   cnt    = (int*)w;   w += (size_t)NCNT * 4;
    int*   ptr    = (int*)w;   w += ((size_t)NCNT + 4) * 4;
    int*   cursor = (int*)w;   w += (size_t)NCNT * 4;
    u64*   elist  = (u64*)w;   w += (size_t)14 * NE * 8 + 64;
    int*   tot    = (int*)w;   w += (NSCB + 1) * 4;

    dim3 blk(256);
    const int gRows = (NN + 63) / 64;

    // CSR build
    hipMemsetAsync(cnt, 0, (size_t)NCNT * 4, stream);
    k_count<<<2048, blk, 0, stream>>>(idx, mask, cnt);
    k_scanA<<<NSCB, blk, 0, stream>>>(cnt, ptr, tot);
    k_scanC<<<NSCB, blk, 0, stream>>>(ptr, cursor, tot);
    k_fill<<<2048, blk, 0, stream>>>(idx, mask, cursor, elist);
    k_sortseg<<<2048, blk, 0, stream>>>(ptr, elist);

    // weights -> bf16 (+ nodes slice of the output)
    k_cvt_all<<<1024, blk, 0, stream>>>(in2W, seg2W, metaW, ctrW, ctr2W, edgeW,
                                        wIn2, wSeg2, wMeta, wCtr, wCtr2, wEdge,
                                        nodes, out);

    // encoders
    k_in<<<gRows, blk, 0, stream>>>(nodes, in1W, in1b, wIn2, ing, inbg,
                                    seg1W, seg1b, wSeg2, segg, segbg, preB);
    k_meta<<<gRows, blk, 0, stream>>>(preB, nodes, wMeta, metag, metabg, featB0);

    // 4 rounds; last round writes d_out directly
    bf16* bufs[2] = { featB0, featB1 };
    for (int i = 0; i < 4; ++i) {
        k_round<<<gRows, dim3(512), 0, stream>>>(bufs[i & 1], ptr, (const int*)elist,
                                                 wEdge + (size_t)i * 14 * 16384,
                                                 wCtr + (size_t)i * 16384,
                                                 wCtr2 + (size_t)i * 16384,
                                                 normg + i * 128, normbg + i * 128,
                                                 ctr2g + i * 128, ctr2bg + i * 128,
                                                 bufs[(i + 1) & 1], out,
                                                 i == 3 ? 1 : 0);
    }
}